// Round 1
// baseline (190.384 us; speedup 1.0000x reference)
//
#include <hip/hip_runtime.h>
#include <math.h>

#define BB 16
#define SS 2048
#define DD 768

// 1/sqrt(768); folded into q0 so kq partials (and hence scores) come out pre-scaled.
#define NORM_SCALE 0.036084391824351615f

#define ECH2 16          // e-chunks for the fused q0+kq kernel
#define EPC2 (DD / ECH2) // 48 e per chunk

#define RPC 16           // rows per flash chunk
#define NCH (SS / RPC)   // 128 chunks per batch

#define ESEG 8           // e-segments for the fused combine+output kernel
#define EPB (DD / ESEG)  // 96 e-rows per block

// ---------------------------------------------------------------------------
// Fused q0 + kq partial. Block (echunk, b), 192 threads.
// Phase 1: q0 slice  q0s[e] = NORM * dot(x[b,0,:], Wq[e0+e,:])   e in [0,48)
//          (4 threads per e, interleaved float4s, LDS tree reduce)
// Phase 2: kq_part[b][echunk][d] = sum_{e in chunk} q0s[e] * Wk[e0+e, d]
//          (thread t owns float4 column t — perfectly coalesced Wk reads)
// No atomics, no zero-init, no q0 global round-trip. flash sums the 16
// partials per batch.
// ---------------------------------------------------------------------------
__global__ void __launch_bounds__(192) qk_fused_kernel(
        const float* __restrict__ x, const float* __restrict__ Wq,
        const float* __restrict__ Wk, float* __restrict__ kq_part) {
    __shared__ float4 xs4[192];   // x[b,0,:] staged once (3 KB)
    __shared__ float part[192];
    __shared__ float q0s[EPC2];
    int ec = blockIdx.x;
    int b  = blockIdx.y;
    int t  = threadIdx.x;
    int e0 = ec * EPC2;

    const float4* xr = (const float4*)(x + (size_t)b * SS * DD);  // row 0
    xs4[t] = xr[t];
    __syncthreads();

    // phase 1: 48 e's x 4 threads each; thread i of group g dots float4s 4j+i
    int g = t >> 2, i = t & 3;
    const float4* wq = (const float4*)(Wq + (size_t)(e0 + g) * DD);
    float acc = 0.f;
#pragma unroll 8
    for (int j = 0; j < 48; ++j) {
        float4 xv = xs4[j * 4 + i];
        float4 wv = wq[j * 4 + i];
        acc += xv.x * wv.x + xv.y * wv.y + xv.z * wv.z + xv.w * wv.w;
    }
    part[t] = acc;
    __syncthreads();
    if (t < EPC2)
        q0s[t] = NORM_SCALE *
                 (part[t * 4] + part[t * 4 + 1] + part[t * 4 + 2] + part[t * 4 + 3]);
    __syncthreads();

    // phase 2: split-K partial over this chunk's 48 e's
    const float4* wk = (const float4*)(Wk + (size_t)e0 * DD);
    float4 a = {0.f, 0.f, 0.f, 0.f};
#pragma unroll 4
    for (int e = 0; e < EPC2; ++e) {
        float q  = q0s[e];
        float4 w = wk[e * 192 + t];
        a.x += q * w.x; a.y += q * w.y; a.z += q * w.z; a.w += q * w.w;
    }
    ((float4*)(kq_part + ((size_t)b * ECH2 + ec) * DD))[t] = a;
}

// ---------------------------------------------------------------------------
// Flash pass (the ONLY full read of b_in), register-resident:
// wave w holds rows 4w..4w+3 in 12 float4 registers (loads issued
// back-to-back -> 12 KB in flight per wave), sums the 16 kq partials into
// kf while those loads are in flight, dots + softmax via shuffles, weighted
// row-sum in registers, one 12 KB LDS cross-wave reduce at the end.
// Emits unnormalized chunk partials (m_c, l_c, o_c[768]).
// grid (NCH, BB), 256 threads.
// ---------------------------------------------------------------------------
__global__ void __launch_bounds__(256) flash_kernel(
        const float* __restrict__ x,
        const float* __restrict__ kq_part,
        float* __restrict__ m_part,
        float* __restrict__ l_part,
        float* __restrict__ o_part) {
    __shared__ float4 osh[4 * 192];  // 12 KB: per-wave o partials
    __shared__ float sc[RPC];
    __shared__ float wsum[4];
    int chunk = blockIdx.x;   // 0..NCH-1
    int b     = blockIdx.y;   // 0..BB-1
    int tid   = threadIdx.x;
    int wave  = tid >> 6, lane = tid & 63;
    int s0    = chunk * RPC;

    // 12 independent global loads (4 rows x 3 float4-segments per lane)
    const float4* xr = (const float4*)(x + ((size_t)b * SS + s0 + wave * 4) * DD);
    float4 xv[12];
#pragma unroll
    for (int j = 0; j < 4; ++j)
#pragma unroll
        for (int k = 0; k < 3; ++k)
            xv[j * 3 + k] = xr[j * (DD / 4) + k * 64 + lane];

    // kf = sum of the 16 kq partials (L2-resident; overlaps the xv loads)
    const float4* kp = (const float4*)(kq_part + (size_t)b * ECH2 * DD);
    float4 kf[3];
    kf[0] = kf[1] = kf[2] = make_float4(0.f, 0.f, 0.f, 0.f);
#pragma unroll 4
    for (int ec = 0; ec < ECH2; ++ec) {
#pragma unroll
        for (int k = 0; k < 3; ++k) {
            float4 tv = kp[ec * 192 + k * 64 + lane];
            kf[k].x += tv.x; kf[k].y += tv.y; kf[k].z += tv.z; kf[k].w += tv.w;
        }
    }

    // scores for this wave's 4 rows
#pragma unroll
    for (int j = 0; j < 4; ++j) {
        float acc = 0.f;
#pragma unroll
        for (int k = 0; k < 3; ++k) {
            float4 xx = xv[j * 3 + k];
            acc += xx.x * kf[k].x + xx.y * kf[k].y
                 + xx.z * kf[k].z + xx.w * kf[k].w;
        }
#pragma unroll
        for (int off = 32; off > 0; off >>= 1) acc += __shfl_down(acc, off);
        if (lane == 0) sc[wave * 4 + j] = acc;
    }
    __syncthreads();

    // chunk max (LDS broadcast reads, computed redundantly by every thread)
    float m = sc[0];
#pragma unroll
    for (int r = 1; r < RPC; ++r) m = fmaxf(m, sc[r]);

    // p for this wave's 4 rows: lanes 0..3 compute, broadcast via shuffle
    float pl = (lane < 4) ? expf(sc[wave * 4 + lane] - m) : 0.f;
    float p0 = __shfl(pl, 0), p1 = __shfl(pl, 1);
    float p2 = __shfl(pl, 2), p3 = __shfl(pl, 3);
    if (lane == 0) wsum[wave] = p0 + p1 + p2 + p3;

    // weighted row-sum in registers (col group i = k*64+lane -> cols 4i..4i+3)
#pragma unroll
    for (int k = 0; k < 3; ++k) {
        float4 a;
        a.x = p0 * xv[k].x + p1 * xv[3 + k].x + p2 * xv[6 + k].x + p3 * xv[9 + k].x;
        a.y = p0 * xv[k].y + p1 * xv[3 + k].y + p2 * xv[6 + k].y + p3 * xv[9 + k].y;
        a.z = p0 * xv[k].z + p1 * xv[3 + k].z + p2 * xv[6 + k].z + p3 * xv[9 + k].z;
        a.w = p0 * xv[k].w + p1 * xv[3 + k].w + p2 * xv[6 + k].w + p3 * xv[9 + k].w;
        osh[wave * 192 + k * 64 + lane] = a;
    }
    __syncthreads();

    int pidx = b * NCH + chunk;
    if (tid < 192) {
        float4 s0v = osh[tid], s1 = osh[192 + tid];
        float4 s2 = osh[384 + tid], s3 = osh[576 + tid];
        float4 s;
        s.x = s0v.x + s1.x + s2.x + s3.x;
        s.y = s0v.y + s1.y + s2.y + s3.y;
        s.z = s0v.z + s1.z + s2.z + s3.z;
        s.w = s0v.w + s1.w + s2.w + s3.w;
        ((float4*)(o_part + (size_t)pidx * DD))[tid] = s;
    }
    if (tid == 0) {
        m_part[pidx] = m;
        l_part[pidx] = wsum[0] + wsum[1] + wsum[2] + wsum[3];
    }
}

// ---------------------------------------------------------------------------
// Fused combine + output projection. Block (b, eseg), 192 threads.
//   M = max_c m_c; w_c = exp(m_c - M); l = sum w_c l_c
//   Phase A (redundant per eseg): c[b,:] = (sum_c w_c o_c[:]) / l  -> LDS
//   Phase B: out[b, e] = dot(c, Wv[e,:]) for the block's 96 e-rows
//            (2 threads per row, interleaved float4s, shuffle pair-sum)
// ---------------------------------------------------------------------------
__global__ void __launch_bounds__(192) combine_out_kernel(
        const float* __restrict__ m_part, const float* __restrict__ l_part,
        const float* __restrict__ o_part, const float* __restrict__ Wv,
        float* __restrict__ out) {
    __shared__ float w[NCH];
    __shared__ float4 c4s[192];   // c[b,:] (3 KB)
    __shared__ float bc[2];       // M, 1/l
    int b  = blockIdx.x;
    int es = blockIdx.y;
    int t  = threadIdx.x;

    if (t < 64) {
        float m = fmaxf(m_part[b * NCH + t], m_part[b * NCH + t + 64]);
#pragma unroll
        for (int off = 32; off > 0; off >>= 1) m = fmaxf(m, __shfl_down(m, off));
        if (t == 0) bc[0] = m;
    }
    __syncthreads();
    float M = bc[0];
    if (t < NCH) w[t] = expf(m_part[b * NCH + t] - M);
    __syncthreads();
    if (t < 64) {
        float s = w[t] * l_part[b * NCH + t]
                + w[t + 64] * l_part[b * NCH + t + 64];
#pragma unroll
        for (int off = 32; off > 0; off >>= 1) s += __shfl_down(s, off);
        if (t == 0) bc[1] = 1.f / s;
    }
    __syncthreads();
    float inv = bc[1];

    // Phase A: thread t owns float4 column t of c (192 float4 = 768 floats)
    const float4* op4 = (const float4*)(o_part + (size_t)b * NCH * DD);
    float4 a = {0.f, 0.f, 0.f, 0.f};
#pragma unroll 16
    for (int cc = 0; cc < NCH; ++cc) {
        float4 v = op4[(size_t)cc * 192 + t];
        float ww = w[cc];
        a.x += ww * v.x; a.y += ww * v.y; a.z += ww * v.z; a.w += ww * v.w;
    }
    a.x *= inv; a.y *= inv; a.z *= inv; a.w *= inv;
    c4s[t] = a;
    __syncthreads();

    // Phase B: 96 e-rows, 2 threads per row (i = half), interleaved float4s
    int r = t >> 1, i = t & 1;
    int e = es * EPB + r;
    const float4* wv = (const float4*)(Wv + (size_t)e * DD);
    float acc = 0.f;
#pragma unroll 8
    for (int j = 0; j < 96; ++j) {
        float4 wvv = wv[j * 2 + i];
        float4 cv  = c4s[j * 2 + i];
        acc += cv.x * wvv.x + cv.y * wvv.y + cv.z * wvv.z + cv.w * wvv.w;
    }
    acc += __shfl_xor(acc, 1);
    if (i == 0) out[b * DD + e] = acc;
}

extern "C" void kernel_launch(void* const* d_in, const int* in_sizes, int n_in,
                              void* d_out, int out_size, void* d_ws, size_t ws_size,
                              hipStream_t stream) {
    const float* b_in = (const float*)d_in[0];
    // d_in[1] = mask: provably dead (masks whole query rows; only query row 0
    // is returned and row 0 is always unmasked) -- unused.
    const float* Wq = (const float*)d_in[2];
    const float* Wk = (const float*)d_in[3];
    const float* Wv = (const float*)d_in[4];
    float* out = (float*)d_out;

    float* ws      = (float*)d_ws;
    float* kq_part = ws;                            // BB*ECH2*DD (786 KB)
    float* m_part  = kq_part + (size_t)BB * ECH2 * DD;  // BB*NCH
    float* l_part  = m_part + BB * NCH;             // BB*NCH
    float* o_part  = l_part + BB * NCH;             // BB*NCH*DD (6.3 MB)

    // 1) kq_part[b][ec][:] = partial of (NORM * x0 @ Wq^T) @ Wk  (no atomics)
    qk_fused_kernel<<<dim3(ECH2, BB), 192, 0, stream>>>(b_in, Wq, Wk, kq_part);
    // 2) single pass over b_in: sums kq partials, scores+softmax+weighted sums
    flash_kernel<<<dim3(NCH, BB), 256, 0, stream>>>(b_in, kq_part,
                                                    m_part, l_part, o_part);
    // 3) combine chunk partials and project through Wv in one kernel
    combine_out_kernel<<<dim3(BB, ESEG), 192, 0, stream>>>(m_part, l_part,
                                                           o_part, Wv, out);
}

// Round 2
// 189.138 us; speedup vs baseline: 1.0066x; 1.0066x over previous
//
#include <hip/hip_runtime.h>
#include <math.h>

#define BB 16
#define SS 2048
#define DD 768

// 1/sqrt(768); folded into q0 so kqs (and hence scores) come out pre-scaled.
#define NORM_SCALE 0.036084391824351615f

#define ECH2 16          // e-chunks for the fused q0+kq kernel
#define EPC2 (DD / ECH2) // 48 e per chunk

#define RPC 16           // rows per flash chunk
#define NCH (SS / RPC)   // 128 chunks per batch

#define ESEG 8           // e-segments for the fused combine+output kernel
#define EPB (DD / ESEG)  // 96 e-rows per block

// ---------------------------------------------------------------------------
// Fused q0 + kq partial. Block (echunk, b), 192 threads.
// Phase 1: q0 slice  q0s[e] = NORM * dot(x[b,0,:], Wq[e0+e,:])   e in [0,48)
// Phase 2: kq_part[b][echunk][d] = sum_{e in chunk} q0s[e] * Wk[e0+e, d]
// No atomics, no zero-init, no q0 global round-trip.
// ---------------------------------------------------------------------------
__global__ void __launch_bounds__(192) qk_fused_kernel(
        const float* __restrict__ x, const float* __restrict__ Wq,
        const float* __restrict__ Wk, float* __restrict__ kq_part) {
    __shared__ float4 xs4[192];   // x[b,0,:] staged once (3 KB)
    __shared__ float part[192];
    __shared__ float q0s[EPC2];
    int ec = blockIdx.x;
    int b  = blockIdx.y;
    int t  = threadIdx.x;
    int e0 = ec * EPC2;

    const float4* xr = (const float4*)(x + (size_t)b * SS * DD);  // row 0
    xs4[t] = xr[t];
    __syncthreads();

    // phase 1: 48 e's x 4 threads each; thread i of group g dots float4s 4j+i
    int g = t >> 2, i = t & 3;
    const float4* wq = (const float4*)(Wq + (size_t)(e0 + g) * DD);
    float acc = 0.f;
#pragma unroll 8
    for (int j = 0; j < 48; ++j) {
        float4 xv = xs4[j * 4 + i];
        float4 wv = wq[j * 4 + i];
        acc += xv.x * wv.x + xv.y * wv.y + xv.z * wv.z + xv.w * wv.w;
    }
    part[t] = acc;
    __syncthreads();
    if (t < EPC2)
        q0s[t] = NORM_SCALE *
                 (part[t * 4] + part[t * 4 + 1] + part[t * 4 + 2] + part[t * 4 + 3]);
    __syncthreads();

    // phase 2: split-K partial over this chunk's 48 e's
    const float4* wk = (const float4*)(Wk + (size_t)e0 * DD);
    float4 a = {0.f, 0.f, 0.f, 0.f};
#pragma unroll 4
    for (int e = 0; e < EPC2; ++e) {
        float q  = q0s[e];
        float4 w = wk[e * 192 + t];
        a.x += q * w.x; a.y += q * w.y; a.z += q * w.z; a.w += q * w.w;
    }
    ((float4*)(kq_part + ((size_t)b * ECH2 + ec) * DD))[t] = a;
}

// ---------------------------------------------------------------------------
// kq reduce: kqs[b][:] = sum_ec kq_part[b][ec][:]
// grid (BB*3) blocks x 64 threads; block j owns b = j/3, float4 segment j%3.
// 786 KB of L2-resident reads, deterministic, ~2 us. Keeps the 16-partial
// summation OUT of the 8192-wave flash kernel (the R1 regression: doing this
// per flash-wave cost ~7 us of VALU+L2 across the grid).
// ---------------------------------------------------------------------------
__global__ void __launch_bounds__(64) kq_reduce_kernel(
        const float* __restrict__ kq_part, float* __restrict__ kqs) {
    int b   = blockIdx.x / 3;
    int seg = blockIdx.x % 3;
    int t   = threadIdx.x;
    int idx = seg * 64 + t;   // float4 index within the 192-wide row
    const float4* kp4 = (const float4*)(kq_part + (size_t)b * ECH2 * DD);
    float4 a = {0.f, 0.f, 0.f, 0.f};
#pragma unroll
    for (int ec = 0; ec < ECH2; ++ec) {
        float4 v = kp4[ec * 192 + idx];
        a.x += v.x; a.y += v.y; a.z += v.z; a.w += v.w;
    }
    ((float4*)(kqs + (size_t)b * DD))[idx] = a;
}

// ---------------------------------------------------------------------------
// Flash pass (the ONLY full read of b_in), register-resident:
// wave w holds rows 4w..4w+3 in 12 float4 registers (loads issued
// back-to-back -> 12 KB in flight per wave), dots + softmax via shuffles,
// weighted row-sum in registers, one 12 KB LDS cross-wave reduce at the end.
// Emits unnormalized chunk partials (m_c, l_c, o_c[768]).
// grid (NCH, BB), 256 threads.
// ---------------------------------------------------------------------------
__global__ void __launch_bounds__(256) flash_kernel(
        const float* __restrict__ x,
        const float* __restrict__ kqs,
        float* __restrict__ m_part,
        float* __restrict__ l_part,
        float* __restrict__ o_part) {
    __shared__ float4 osh[4 * 192];  // 12 KB: per-wave o partials
    __shared__ float sc[RPC];
    __shared__ float wsum[4];
    int chunk = blockIdx.x;   // 0..NCH-1
    int b     = blockIdx.y;   // 0..BB-1
    int tid   = threadIdx.x;
    int wave  = tid >> 6, lane = tid & 63;
    int s0    = chunk * RPC;

    // 12 independent global loads (4 rows x 3 float4-segments per lane)
    const float4* xr = (const float4*)(x + ((size_t)b * SS + s0 + wave * 4) * DD);
    float4 xv[12];
#pragma unroll
    for (int j = 0; j < 4; ++j)
#pragma unroll
        for (int k = 0; k < 3; ++k)
            xv[j * 3 + k] = xr[j * (DD / 4) + k * 64 + lane];

    const float4* kr = (const float4*)(kqs + b * DD);
    float4 kf[3];
#pragma unroll
    for (int k = 0; k < 3; ++k) kf[k] = kr[k * 64 + lane];

    // scores for this wave's 4 rows
#pragma unroll
    for (int j = 0; j < 4; ++j) {
        float acc = 0.f;
#pragma unroll
        for (int k = 0; k < 3; ++k) {
            float4 xx = xv[j * 3 + k];
            acc += xx.x * kf[k].x + xx.y * kf[k].y
                 + xx.z * kf[k].z + xx.w * kf[k].w;
        }
#pragma unroll
        for (int off = 32; off > 0; off >>= 1) acc += __shfl_down(acc, off);
        if (lane == 0) sc[wave * 4 + j] = acc;
    }
    __syncthreads();

    // chunk max (LDS broadcast reads, computed redundantly by every thread)
    float m = sc[0];
#pragma unroll
    for (int r = 1; r < RPC; ++r) m = fmaxf(m, sc[r]);

    // p for this wave's 4 rows: lanes 0..3 compute, broadcast via shuffle
    float pl = (lane < 4) ? expf(sc[wave * 4 + lane] - m) : 0.f;
    float p0 = __shfl(pl, 0), p1 = __shfl(pl, 1);
    float p2 = __shfl(pl, 2), p3 = __shfl(pl, 3);
    if (lane == 0) wsum[wave] = p0 + p1 + p2 + p3;

    // weighted row-sum in registers (col group i = k*64+lane -> cols 4i..4i+3)
#pragma unroll
    for (int k = 0; k < 3; ++k) {
        float4 a;
        a.x = p0 * xv[k].x + p1 * xv[3 + k].x + p2 * xv[6 + k].x + p3 * xv[9 + k].x;
        a.y = p0 * xv[k].y + p1 * xv[3 + k].y + p2 * xv[6 + k].y + p3 * xv[9 + k].y;
        a.z = p0 * xv[k].z + p1 * xv[3 + k].z + p2 * xv[6 + k].z + p3 * xv[9 + k].z;
        a.w = p0 * xv[k].w + p1 * xv[3 + k].w + p2 * xv[6 + k].w + p3 * xv[9 + k].w;
        osh[wave * 192 + k * 64 + lane] = a;
    }
    __syncthreads();

    int pidx = b * NCH + chunk;
    if (tid < 192) {
        float4 s0v = osh[tid], s1 = osh[192 + tid];
        float4 s2 = osh[384 + tid], s3 = osh[576 + tid];
        float4 s;
        s.x = s0v.x + s1.x + s2.x + s3.x;
        s.y = s0v.y + s1.y + s2.y + s3.y;
        s.z = s0v.z + s1.z + s2.z + s3.z;
        s.w = s0v.w + s1.w + s2.w + s3.w;
        ((float4*)(o_part + (size_t)pidx * DD))[tid] = s;
    }
    if (tid == 0) {
        m_part[pidx] = m;
        l_part[pidx] = wsum[0] + wsum[1] + wsum[2] + wsum[3];
    }
}

// ---------------------------------------------------------------------------
// Fused combine + output projection. Block (b, eseg), 192 threads.
//   M = max_c m_c; w_c = exp(m_c - M); l = sum w_c l_c
//   Phase A (redundant per eseg): c[b,:] = (sum_c w_c o_c[:]) / l  -> LDS
//   Phase B: out[b, e] = dot(c, Wv[e,:]) for the block's 96 e-rows
// ---------------------------------------------------------------------------
__global__ void __launch_bounds__(192) combine_out_kernel(
        const float* __restrict__ m_part, const float* __restrict__ l_part,
        const float* __restrict__ o_part, const float* __restrict__ Wv,
        float* __restrict__ out) {
    __shared__ float w[NCH];
    __shared__ float4 c4s[192];   // c[b,:] (3 KB)
    __shared__ float bc[2];       // M, 1/l
    int b  = blockIdx.x;
    int es = blockIdx.y;
    int t  = threadIdx.x;

    if (t < 64) {
        float m = fmaxf(m_part[b * NCH + t], m_part[b * NCH + t + 64]);
#pragma unroll
        for (int off = 32; off > 0; off >>= 1) m = fmaxf(m, __shfl_down(m, off));
        if (t == 0) bc[0] = m;
    }
    __syncthreads();
    float M = bc[0];
    if (t < NCH) w[t] = expf(m_part[b * NCH + t] - M);
    __syncthreads();
    if (t < 64) {
        float s = w[t] * l_part[b * NCH + t]
                + w[t + 64] * l_part[b * NCH + t + 64];
#pragma unroll
        for (int off = 32; off > 0; off >>= 1) s += __shfl_down(s, off);
        if (t == 0) bc[1] = 1.f / s;
    }
    __syncthreads();
    float inv = bc[1];

    // Phase A: thread t owns float4 column t of c (192 float4 = 768 floats)
    const float4* op4 = (const float4*)(o_part + (size_t)b * NCH * DD);
    float4 a = {0.f, 0.f, 0.f, 0.f};
#pragma unroll 16
    for (int cc = 0; cc < NCH; ++cc) {
        float4 v = op4[(size_t)cc * 192 + t];
        float ww = w[cc];
        a.x += ww * v.x; a.y += ww * v.y; a.z += ww * v.z; a.w += ww * v.w;
    }
    a.x *= inv; a.y *= inv; a.z *= inv; a.w *= inv;
    c4s[t] = a;
    __syncthreads();

    // Phase B: 96 e-rows, 2 threads per row (i = half), interleaved float4s
    int r = t >> 1, i = t & 1;
    int e = es * EPB + r;
    const float4* wv = (const float4*)(Wv + (size_t)e * DD);
    float acc = 0.f;
#pragma unroll 8
    for (int j = 0; j < 96; ++j) {
        float4 wvv = wv[j * 2 + i];
        float4 cv  = c4s[j * 2 + i];
        acc += cv.x * wvv.x + cv.y * wvv.y + cv.z * wvv.z + cv.w * wvv.w;
    }
    acc += __shfl_xor(acc, 1);
    if (i == 0) out[b * DD + e] = acc;
}

extern "C" void kernel_launch(void* const* d_in, const int* in_sizes, int n_in,
                              void* d_out, int out_size, void* d_ws, size_t ws_size,
                              hipStream_t stream) {
    const float* b_in = (const float*)d_in[0];
    // d_in[1] = mask: provably dead (masks whole query rows; only query row 0
    // is returned and row 0 is always unmasked) -- unused.
    const float* Wq = (const float*)d_in[2];
    const float* Wk = (const float*)d_in[3];
    const float* Wv = (const float*)d_in[4];
    float* out = (float*)d_out;

    float* ws      = (float*)d_ws;
    float* kq_part = ws;                                 // BB*ECH2*DD (786 KB)
    float* kqs     = kq_part + (size_t)BB * ECH2 * DD;   // BB*DD
    float* m_part  = kqs + BB * DD;                      // BB*NCH
    float* l_part  = m_part + BB * NCH;                  // BB*NCH
    float* o_part  = l_part + BB * NCH;                  // BB*NCH*DD (6.3 MB)

    // 1) kq_part[b][ec][:] = partial of (NORM * x0 @ Wq^T) @ Wk  (no atomics)
    qk_fused_kernel<<<dim3(ECH2, BB), 192, 0, stream>>>(b_in, Wq, Wk, kq_part);
    // 2) kqs = sum of the 16 partials (tiny, keeps the sum out of flash)
    kq_reduce_kernel<<<BB * 3, 64, 0, stream>>>(kq_part, kqs);
    // 3) single pass over b_in: scores+softmax+weighted sums, register-resident
    flash_kernel<<<dim3(NCH, BB), 256, 0, stream>>>(b_in, kqs,
                                                    m_part, l_part, o_part);
    // 4) combine chunk partials and project through Wv in one kernel
    combine_out_kernel<<<dim3(BB, ESEG), 192, 0, stream>>>(m_part, l_part,
                                                           o_part, Wv, out);
}

// Round 3
// 183.017 us; speedup vs baseline: 1.0403x; 1.0334x over previous
//
#include <hip/hip_runtime.h>
#include <math.h>

#define BB 16
#define SS 2048
#define DD 768

// 1/sqrt(768); folded into q0 so kqs (and hence scores) come out pre-scaled.
#define NORM_SCALE 0.036084391824351615f

#define ECH2 16          // e-chunks for the fused q0+kq kernel
#define EPC2 (DD / ECH2) // 48 e per chunk

#define RPC 16           // rows per flash chunk
#define NCH (SS / RPC)   // 128 chunks per batch

// ---------------------------------------------------------------------------
// Fused q0 + kq partial. Block (echunk, b), 192 threads.
// Phase 1: q0 slice  q0s[e] = NORM * dot(x[b,0,:], Wq[e0+e,:])   e in [0,48)
// Phase 2: kq_part[b][echunk][d] = sum_{e in chunk} q0s[e] * Wk[e0+e, d]
// No atomics, no zero-init, no q0 global round-trip. Wq/Wk each read once.
// ---------------------------------------------------------------------------
__global__ void __launch_bounds__(192) qk_fused_kernel(
        const float* __restrict__ x, const float* __restrict__ Wq,
        const float* __restrict__ Wk, float* __restrict__ kq_part) {
    __shared__ float4 xs4[192];   // x[b,0,:] staged once (3 KB)
    __shared__ float part[192];
    __shared__ float q0s[EPC2];
    int ec = blockIdx.x;
    int b  = blockIdx.y;
    int t  = threadIdx.x;
    int e0 = ec * EPC2;

    const float4* xr = (const float4*)(x + (size_t)b * SS * DD);  // row 0
    xs4[t] = xr[t];
    __syncthreads();

    // phase 1: 48 e's x 4 threads each; thread i of group g dots float4s 4j+i
    int g = t >> 2, i = t & 3;
    const float4* wq = (const float4*)(Wq + (size_t)(e0 + g) * DD);
    float acc = 0.f;
#pragma unroll 8
    for (int j = 0; j < 48; ++j) {
        float4 xv = xs4[j * 4 + i];
        float4 wv = wq[j * 4 + i];
        acc += xv.x * wv.x + xv.y * wv.y + xv.z * wv.z + xv.w * wv.w;
    }
    part[t] = acc;
    __syncthreads();
    if (t < EPC2)
        q0s[t] = NORM_SCALE *
                 (part[t * 4] + part[t * 4 + 1] + part[t * 4 + 2] + part[t * 4 + 3]);
    __syncthreads();

    // phase 2: split-K partial over this chunk's 48 e's
    const float4* wk = (const float4*)(Wk + (size_t)e0 * DD);
    float4 a = {0.f, 0.f, 0.f, 0.f};
#pragma unroll 4
    for (int e = 0; e < EPC2; ++e) {
        float q  = q0s[e];
        float4 w = wk[e * 192 + t];
        a.x += q * w.x; a.y += q * w.y; a.z += q * w.z; a.w += q * w.w;
    }
    ((float4*)(kq_part + ((size_t)b * ECH2 + ec) * DD))[t] = a;
}

// ---------------------------------------------------------------------------
// kq reduce: kqs[b][:] = sum_ec kq_part[b][ec][:]
// grid (BB*3) x 64 threads; block j owns b = j/3, float4 segment j%3.
// 786 KB L2-resident, deterministic, keeps the sum out of the 8192-wave flash.
// ---------------------------------------------------------------------------
__global__ void __launch_bounds__(64) kq_reduce_kernel(
        const float* __restrict__ kq_part, float* __restrict__ kqs) {
    int b   = blockIdx.x / 3;
    int seg = blockIdx.x % 3;
    int t   = threadIdx.x;
    int idx = seg * 64 + t;   // float4 index within the 192-wide row
    const float4* kp4 = (const float4*)(kq_part + (size_t)b * ECH2 * DD);
    float4 a = {0.f, 0.f, 0.f, 0.f};
#pragma unroll
    for (int ec = 0; ec < ECH2; ++ec) {
        float4 v = kp4[ec * 192 + idx];
        a.x += v.x; a.y += v.y; a.z += v.z; a.w += v.w;
    }
    ((float4*)(kqs + (size_t)b * DD))[idx] = a;
}

// ---------------------------------------------------------------------------
// Flash pass (the ONLY full read of b_in), register-resident:
// wave w holds rows 4w..4w+3 in 12 float4 registers (loads issued
// back-to-back -> 12 KB in flight per wave), dots + softmax via shuffles,
// weighted row-sum in registers, one 12 KB LDS cross-wave reduce at the end.
// Emits unnormalized chunk partials (m_c, l_c, o_c[768]).
// grid (NCH, BB), 256 threads.
// ---------------------------------------------------------------------------
__global__ void __launch_bounds__(256) flash_kernel(
        const float* __restrict__ x,
        const float* __restrict__ kqs,
        float* __restrict__ m_part,
        float* __restrict__ l_part,
        float* __restrict__ o_part) {
    __shared__ float4 osh[4 * 192];  // 12 KB: per-wave o partials
    __shared__ float sc[RPC];
    __shared__ float wsum[4];
    int chunk = blockIdx.x;   // 0..NCH-1
    int b     = blockIdx.y;   // 0..BB-1
    int tid   = threadIdx.x;
    int wave  = tid >> 6, lane = tid & 63;
    int s0    = chunk * RPC;

    // 12 independent global loads (4 rows x 3 float4-segments per lane)
    const float4* xr = (const float4*)(x + ((size_t)b * SS + s0 + wave * 4) * DD);
    float4 xv[12];
#pragma unroll
    for (int j = 0; j < 4; ++j)
#pragma unroll
        for (int k = 0; k < 3; ++k)
            xv[j * 3 + k] = xr[j * (DD / 4) + k * 64 + lane];

    const float4* kr = (const float4*)(kqs + b * DD);
    float4 kf[3];
#pragma unroll
    for (int k = 0; k < 3; ++k) kf[k] = kr[k * 64 + lane];

    // scores for this wave's 4 rows
#pragma unroll
    for (int j = 0; j < 4; ++j) {
        float acc = 0.f;
#pragma unroll
        for (int k = 0; k < 3; ++k) {
            float4 xx = xv[j * 3 + k];
            acc += xx.x * kf[k].x + xx.y * kf[k].y
                 + xx.z * kf[k].z + xx.w * kf[k].w;
        }
#pragma unroll
        for (int off = 32; off > 0; off >>= 1) acc += __shfl_down(acc, off);
        if (lane == 0) sc[wave * 4 + j] = acc;
    }
    __syncthreads();

    // chunk max (LDS broadcast reads, computed redundantly by every thread)
    float m = sc[0];
#pragma unroll
    for (int r = 1; r < RPC; ++r) m = fmaxf(m, sc[r]);

    // p for this wave's 4 rows: lanes 0..3 compute, broadcast via shuffle
    float pl = (lane < 4) ? expf(sc[wave * 4 + lane] - m) : 0.f;
    float p0 = __shfl(pl, 0), p1 = __shfl(pl, 1);
    float p2 = __shfl(pl, 2), p3 = __shfl(pl, 3);
    if (lane == 0) wsum[wave] = p0 + p1 + p2 + p3;

    // weighted row-sum in registers (col group i = k*64+lane -> cols 4i..4i+3)
#pragma unroll
    for (int k = 0; k < 3; ++k) {
        float4 a;
        a.x = p0 * xv[k].x + p1 * xv[3 + k].x + p2 * xv[6 + k].x + p3 * xv[9 + k].x;
        a.y = p0 * xv[k].y + p1 * xv[3 + k].y + p2 * xv[6 + k].y + p3 * xv[9 + k].y;
        a.z = p0 * xv[k].z + p1 * xv[3 + k].z + p2 * xv[6 + k].z + p3 * xv[9 + k].z;
        a.w = p0 * xv[k].w + p1 * xv[3 + k].w + p2 * xv[6 + k].w + p3 * xv[9 + k].w;
        osh[wave * 192 + k * 64 + lane] = a;
    }
    __syncthreads();

    int pidx = b * NCH + chunk;
    if (tid < 192) {
        float4 s0v = osh[tid], s1 = osh[192 + tid];
        float4 s2 = osh[384 + tid], s3 = osh[576 + tid];
        float4 s;
        s.x = s0v.x + s1.x + s2.x + s3.x;
        s.y = s0v.y + s1.y + s2.y + s3.y;
        s.z = s0v.z + s1.z + s2.z + s3.z;
        s.w = s0v.w + s1.w + s2.w + s3.w;
        ((float4*)(o_part + (size_t)pidx * DD))[tid] = s;
    }
    if (tid == 0) {
        m_part[pidx] = m;
        l_part[pidx] = wsum[0] + wsum[1] + wsum[2] + wsum[3];
    }
}

// ---------------------------------------------------------------------------
// Combine: per (batch, column-segment) block (R0 structure — o_part read
// EXACTLY once across blocks; c round-trips through global, 49 KB):
//   M = max_c m_c; w_c = exp(m_c - M); l = sum w_c l_c
//   c[b,col] = (sum_c w_c o_c[col]) / l
// grid (BB, 3), 256 threads; wave-parallel M and l reductions.
// ---------------------------------------------------------------------------
__global__ void combine_kernel(const float* __restrict__ m_part,
                               const float* __restrict__ l_part,
                               const float* __restrict__ o_part,
                               float* __restrict__ c) {
    __shared__ float w[NCH];
    __shared__ float bc[2];  // M, 1/l
    int b   = blockIdx.x;
    int seg = blockIdx.y;
    int tid = threadIdx.x;

    if (tid < 64) {
        float m = fmaxf(m_part[b * NCH + tid], m_part[b * NCH + tid + 64]);
#pragma unroll
        for (int off = 32; off > 0; off >>= 1) m = fmaxf(m, __shfl_down(m, off));
        if (tid == 0) bc[0] = m;
    }
    __syncthreads();
    float M = bc[0];
    if (tid < NCH) w[tid] = expf(m_part[b * NCH + tid] - M);
    __syncthreads();
    if (tid < 64) {
        float s = w[tid] * l_part[b * NCH + tid]
                + w[tid + 64] * l_part[b * NCH + tid + 64];
#pragma unroll
        for (int off = 32; off > 0; off >>= 1) s += __shfl_down(s, off);
        if (tid == 0) bc[1] = 1.f / s;
    }
    __syncthreads();
    float inv = bc[1];

    int col = seg * 256 + tid;
    const float* op = o_part + (size_t)b * NCH * DD + col;
    float a = 0.f;
#pragma unroll 8
    for (int cc = 0; cc < NCH; ++cc) a += w[cc] * op[(size_t)cc * DD];
    c[b * DD + col] = a * inv;
}

// ---------------------------------------------------------------------------
// Output projection: out[wid] = dot(c[b*DD : +DD], Wv[e*DD : +DD]),
// wid = b*DD + e. One wave per output element, float4 loads (R0 structure).
// ---------------------------------------------------------------------------
__global__ void out_proj_kernel(const float* __restrict__ c,
                                const float* __restrict__ Wv,
                                float* __restrict__ out) {
    int wid  = blockIdx.x * 4 + (threadIdx.x >> 6);
    int lane = threadIdx.x & 63;
    int b = wid / DD;
    int e = wid % DD;
    const float4* xr = (const float4*)(c + (size_t)b * DD);
    const float4* wr = (const float4*)(Wv + (size_t)e * DD);
    float acc = 0.f;
#pragma unroll
    for (int k = 0; k < 3; ++k) {
        float4 xv = xr[lane + k * 64];
        float4 wv = wr[lane + k * 64];
        acc += xv.x * wv.x + xv.y * wv.y + xv.z * wv.z + xv.w * wv.w;
    }
#pragma unroll
    for (int off = 32; off > 0; off >>= 1) acc += __shfl_down(acc, off);
    if (lane == 0) out[wid] = acc;
}

extern "C" void kernel_launch(void* const* d_in, const int* in_sizes, int n_in,
                              void* d_out, int out_size, void* d_ws, size_t ws_size,
                              hipStream_t stream) {
    const float* b_in = (const float*)d_in[0];
    // d_in[1] = mask: provably dead (masks whole query rows; only query row 0
    // is returned and row 0 is always unmasked) -- unused.
    const float* Wq = (const float*)d_in[2];
    const float* Wk = (const float*)d_in[3];
    const float* Wv = (const float*)d_in[4];
    float* out = (float*)d_out;

    float* ws      = (float*)d_ws;
    float* kq_part = ws;                                 // BB*ECH2*DD (786 KB)
    float* kqs     = kq_part + (size_t)BB * ECH2 * DD;   // BB*DD
    float* m_part  = kqs + BB * DD;                      // BB*NCH
    float* l_part  = m_part + BB * NCH;                  // BB*NCH
    float* o_part  = l_part + BB * NCH;                  // BB*NCH*DD (6.3 MB)
    float* c       = o_part + (size_t)BB * NCH * DD;     // BB*DD

    // 1) kq_part[b][ec][:] = partial of (NORM * x0 @ Wq^T) @ Wk  (no atomics)
    qk_fused_kernel<<<dim3(ECH2, BB), 192, 0, stream>>>(b_in, Wq, Wk, kq_part);
    // 2) kqs = sum of the 16 partials (tiny, keeps the sum out of flash)
    kq_reduce_kernel<<<BB * 3, 64, 0, stream>>>(kq_part, kqs);
    // 3) single pass over b_in: scores+softmax+weighted sums, register-resident
    flash_kernel<<<dim3(NCH, BB), 256, 0, stream>>>(b_in, kqs,
                                                    m_part, l_part, o_part);
    // 4) combine chunk partials -> c[b,:]  (o_part read exactly once)
    combine_kernel<<<dim3(BB, 3), 256, 0, stream>>>(m_part, l_part, o_part, c);
    // 5) out = c @ Wv^T
    out_proj_kernel<<<BB * DD / 4, 256, 0, stream>>>(c, Wv, out);
}